// Round 13
// baseline (459.482 us; speedup 1.0000x reference)
//
#include <hip/hip_runtime.h>
#include <hip/hip_bf16.h>
#include <math.h>

// Problem constants
#define MTOT   100352        // B*H*W tokens = 2048 windows * 49
#define CC     192
#define SCALEQ 0.17677669529663687f   // 32^-0.5

typedef __attribute__((ext_vector_type(8))) short short8;
typedef __attribute__((ext_vector_type(4))) float f32x4;

__device__ __forceinline__ float b2f(unsigned short u) {
  return __uint_as_float(((unsigned int)u) << 16);
}

__device__ __forceinline__ void async_copy16(const void* g, void* l) {
  __builtin_amdgcn_global_load_lds(
      (const __attribute__((address_space(1))) unsigned int*)g,
      (__attribute__((address_space(3))) unsigned int*)l,
      16, 0, 0);
}

// ---------------------------------------------------------------------------
// Weight fp32 -> bf16 conversion (4 weight matrices concatenated into dst)
// ---------------------------------------------------------------------------
__global__ void cvt4_kernel(const float* __restrict__ s0, int n0,
                            const float* __restrict__ s1, int n1,
                            const float* __restrict__ s2, int n2,
                            const float* __restrict__ s3, int n3,
                            __hip_bfloat16* __restrict__ dst)
{
  int total = n0 + n1 + n2 + n3;
  for (int i = blockIdx.x * blockDim.x + threadIdx.x; i < total;
       i += gridDim.x * blockDim.x) {
    int j = i; const float* s;
    if (j < n0) s = s0;
    else { j -= n0; if (j < n1) s = s1;
      else { j -= n1; if (j < n2) s = s2; else { j -= n2; s = s3; } } }
    dst[i] = __float2bfloat16(s[j]);
  }
}

// ---------------------------------------------------------------------------
// Softmax-bias table: tab[wm][head][q64][k64] = rpb(q,k,head) + mask[wm][q][k]
// ---------------------------------------------------------------------------
__global__ __launch_bounds__(256)
void smtab_kernel(const float* __restrict__ mask, const float* __restrict__ rpb,
                  __hip_bfloat16* __restrict__ tab)
{
  const int wh = blockIdx.x;          // 0..383 = wm*6 + head
  const int wm = wh / 6, head = wh - wm * 6;
  for (int u = threadIdx.x; u < 4096; u += 256) {
    int q = u >> 6, k = u & 63;
    float v = -1e30f;
    if (q < 49 && k < 49) {
      int r1 = q / 7, s1 = q - r1 * 7, r2 = k / 7, s2 = k - r2 * 7;
      v = rpb[((r1 - r2 + 6) * 13 + (s1 - s2 + 6)) * 6 + head]
        + mask[wm * 2401 + q * 49 + k];
    }
    tab[(size_t)wh * 4096 + u] = __float2bfloat16(v);
  }
}

// ---------------------------------------------------------------------------
// LayerNorm (one wave per token). REMAP=true: fused roll(-3,-3)+window
// partition for LN1 (output in window-token order). REMAP=false: LN2.
// ---------------------------------------------------------------------------
template<bool REMAP>
__global__ __launch_bounds__(256)
void ln_kernel(const float* __restrict__ xin, const float* __restrict__ gam,
               const float* __restrict__ bet, __hip_bfloat16* __restrict__ out)
{
  const int wave = threadIdx.x >> 6, lane = threadIdx.x & 63;
  const int m = blockIdx.x * 4 + wave;
  size_t srow;
  if (REMAP) {
    int b_ = m / 49, n = m - b_ * 49;
    int b = b_ >> 6, widx = b_ & 63;
    int wh = widx >> 3, ww = widx & 7;
    int r = n / 7, s = n - r * 7;
    int h = wh * 7 + r, w = ww * 7 + s;
    int sh = h + 3; if (sh >= 56) sh -= 56;
    int sw = w + 3; if (sw >= 56) sw -= 56;
    srow = (size_t)b * 3136 + sh * 56 + sw;
  } else {
    srow = m;
  }
  const float* row = xin + srow * 192;
  float v0 = row[lane], v1 = row[lane + 64], v2 = row[lane + 128];
  float sum = v0 + v1 + v2;
  float sq  = v0 * v0 + v1 * v1 + v2 * v2;
  #pragma unroll
  for (int o = 1; o < 64; o <<= 1) {
    sum += __shfl_xor(sum, o);
    sq  += __shfl_xor(sq, o);
  }
  float mu = sum * (1.f / 192.f);
  float rs = rsqrtf(sq * (1.f / 192.f) - mu * mu + 1e-5f);
  __hip_bfloat16* orow = out + (size_t)m * 192;
  orow[lane]       = __float2bfloat16((v0 - mu) * rs * gam[lane]       + bet[lane]);
  orow[lane + 64]  = __float2bfloat16((v1 - mu) * rs * gam[lane + 64]  + bet[lane + 64]);
  orow[lane + 128] = __float2bfloat16((v2 - mu) * rs * gam[lane + 128] + bet[lane + 128]);
}

// ---------------------------------------------------------------------------
// bf16 MFMA GEMM (dbuf, swizzled, hoisted) — used for qkv (EPI 0) and
// proj (EPI 2). BM=128, BN=64, BK=64, 4 waves, acc[4][2].
// ---------------------------------------------------------------------------
template<int EPI, int K>
__global__ __launch_bounds__(256)
void gemm_kernel(const __hip_bfloat16* __restrict__ A,
                 const __hip_bfloat16* __restrict__ Wt,
                 const float* __restrict__ bias,
                 int Ntot,
                 void* __restrict__ outp,
                 const float* __restrict__ res)
{
  __shared__ __hip_bfloat16 smem[2][12288] __attribute__((aligned(16)));
  const int tid  = threadIdx.x;
  const int wave = tid >> 6;
  const int bn   = blockIdx.x * 64;
  const int bm   = blockIdx.y * 128;

  const int lr = tid & 15;
  const int hi = (tid >> 4) & 3;
  const int wm = (wave >> 1) * 64;
  const int wn = (wave & 1) * 32;

  const __hip_bfloat16* aptr[4];
  const __hip_bfloat16* bptr[2];
  int adst[4], bdst[2];
  #pragma unroll
  for (int p = 0; p < 4; p++) {
    int u = p * 256 + tid;
    int row = u >> 3;
    int c8 = (u & 7) ^ (row & 7);              // inverse swizzle on source
    aptr[p] = A + (size_t)(bm + row) * K + c8 * 8;
    adst[p] = (p * 256 + (wave << 6)) * 8;
  }
  #pragma unroll
  for (int p = 0; p < 2; p++) {
    int u = p * 256 + tid;
    int row = u >> 3;
    int c8 = (u & 7) ^ (row & 7);
    bptr[p] = Wt + (size_t)(bn + row) * K + c8 * 8;
    bdst[p] = 8192 + (p * 256 + (wave << 6)) * 8;
  }

  f32x4 acc[4][2];
  #pragma unroll
  for (int i = 0; i < 4; i++)
    #pragma unroll
    for (int j = 0; j < 2; j++) acc[i][j] = (f32x4){0.f, 0.f, 0.f, 0.f};

  const int KT = K / 64;

  #define STAGE(buf, k0)                                                      \
    do {                                                                      \
      _Pragma("unroll")                                                       \
      for (int p = 0; p < 4; p++)                                             \
        async_copy16(aptr[p] + (k0), &smem[buf][adst[p]]);                    \
      _Pragma("unroll")                                                       \
      for (int p = 0; p < 2; p++)                                             \
        async_copy16(bptr[p] + (k0), &smem[buf][bdst[p]]);                    \
    } while (0)

  STAGE(0, 0);
  __syncthreads();

  #pragma unroll
  for (int kt = 0; kt < KT; kt++) {
    const int cur = kt & 1;
    if (kt + 1 < KT) STAGE(cur ^ 1, (kt + 1) * 64);
    const __hip_bfloat16* sb = smem[cur];
    #pragma unroll
    for (int kk = 0; kk < 2; kk++) {
      short8 af[4], bfr[2];
      #pragma unroll
      for (int mf = 0; mf < 4; mf++) {
        int r = wm + mf * 16 + lr;
        af[mf] = *(const short8*)&sb[r * 64 + ((kk * 32 + hi * 8) ^ ((r & 7) * 8))];
      }
      #pragma unroll
      for (int nf = 0; nf < 2; nf++) {
        int r = wn + nf * 16 + lr;
        bfr[nf] = *(const short8*)&sb[8192 + r * 64 + ((kk * 32 + hi * 8) ^ ((r & 7) * 8))];
      }
      #pragma unroll
      for (int mf = 0; mf < 4; mf++)
        #pragma unroll
        for (int nf = 0; nf < 2; nf++)
          acc[mf][nf] = __builtin_amdgcn_mfma_f32_16x16x32_bf16(
              af[mf], bfr[nf], acc[mf][nf], 0, 0, 0);
    }
    __syncthreads();
  }
  #undef STAGE

  // Epilogue. C/D layout: col = lane&15, row = (lane>>4)*4 + reg.
  #pragma unroll
  for (int mf = 0; mf < 4; mf++) {
    #pragma unroll
    for (int nf = 0; nf < 2; nf++) {
      #pragma unroll
      for (int r = 0; r < 4; r++) {
        int m = bm + wm + mf * 16 + hi * 4 + r;
        int n = bn + wn + nf * 16 + lr;
        float z = acc[mf][nf][r] + bias[n];
        if (EPI == 0) {
          ((__hip_bfloat16*)outp)[(size_t)m * Ntot + n] = __float2bfloat16(z);
        } else {  // EPI == 2: proj + window-reverse + unshift + residual
          int b_ = m / 49, n49 = m - b_ * 49;
          int b = b_ >> 6, widx = b_ & 63;
          int wh = widx >> 3, ww = widx & 7;
          int rr = n49 / 7, ss = n49 - rr * 7;
          int h = wh * 7 + rr, w = ww * 7 + ss;
          int fh = h + 3; if (fh >= 56) fh -= 56;
          int fw = w + 3; if (fw >= 56) fw -= 56;
          size_t rowimg = (size_t)b * 3136 + fh * 56 + fw;
          ((float*)outp)[rowimg * 192 + n] = res[rowimg * 192 + n] + z;
        }
      }
    }
  }
}

// ---------------------------------------------------------------------------
// Fused MLP: out = GELU(ln2 @ W1^T + b1) @ W2^T + b2 + x2
// Block = 64 tokens, 512 threads (8 waves). h (64x768 bf16) lives in LDS —
// eliminates the 308 MB h round-trip through HBM.
// Phase 1: waves split N 8x96 (acc[4][6]); A from LDS (swizzled), W1 from
// global (L2-hot, 295 KB). Phase 2: waves 2(M)x4(N), tile 32x48 (acc[2][3]);
// h from LDS (swizzled), W2 from global (L2-hot). LDS 123 KB -> 1 block/CU.
// ---------------------------------------------------------------------------
__global__ __launch_bounds__(512)
void mlp_kernel(const __hip_bfloat16* __restrict__ ln2,   // [MTOT][192]
                const __hip_bfloat16* __restrict__ W1,    // [768][192]
                const float* __restrict__ b1,
                const __hip_bfloat16* __restrict__ W2,    // [192][768]
                const float* __restrict__ b2,
                const float* __restrict__ x2,             // [MTOT][192] fp32
                float* __restrict__ out)                  // [MTOT][192] fp32
{
  __shared__ __hip_bfloat16 Atile[12288] __attribute__((aligned(16)));  // 64x192
  __shared__ __hip_bfloat16 Htile[49152] __attribute__((aligned(16)));  // 64x768
  const int tid  = threadIdx.x;
  const int wave = tid >> 6;
  const int lr   = tid & 15;
  const int hi   = (tid >> 4) & 3;
  const int tok0 = blockIdx.x * 64;

  // ---- stage A (64x192 bf16 = 24.5 KB): 3 passes x 512 thr x 16B ----
  // linear LDS dest; inverse-swizzled global source chunk (rule #21)
  #pragma unroll
  for (int p = 0; p < 3; p++) {
    int u = p * 512 + tid;               // chunk id 0..1535
    int row = u / 24, c = u % 24;
    int csw = (c & ~7) | ((c & 7) ^ (row & 7));
    async_copy16(ln2 + (size_t)(tok0 + row) * 192 + csw * 8, &Atile[u * 8]);
  }
  __syncthreads();

  // ---- phase 1: h = GELU(A @ W1^T + b1); wave covers h cols wn..wn+95 ----
  {
    const int wn = wave * 96;
    f32x4 acc[4][6];
    #pragma unroll
    for (int i = 0; i < 4; i++)
      #pragma unroll
      for (int j = 0; j < 6; j++) acc[i][j] = (f32x4){0.f, 0.f, 0.f, 0.f};

    #pragma unroll
    for (int kk = 0; kk < 6; kk++) {       // K=192, 32/step
      short8 af[4], bfr[6];
      #pragma unroll
      for (int mf = 0; mf < 4; mf++) {
        int r = mf * 16 + lr;
        int ch = kk * 4 + hi;
        int chs = (ch & ~7) | ((ch & 7) ^ (r & 7));
        af[mf] = *(const short8*)&Atile[r * 192 + chs * 8];
      }
      #pragma unroll
      for (int nf = 0; nf < 6; nf++) {
        int n = wn + nf * 16 + lr;
        bfr[nf] = *(const short8*)(W1 + (size_t)n * 192 + kk * 32 + hi * 8);
      }
      #pragma unroll
      for (int mf = 0; mf < 4; mf++)
        #pragma unroll
        for (int nf = 0; nf < 6; nf++)
          acc[mf][nf] = __builtin_amdgcn_mfma_f32_16x16x32_bf16(
              af[mf], bfr[nf], acc[mf][nf], 0, 0, 0);
    }

    // GELU + store h to LDS (swizzled chunks)
    #pragma unroll
    for (int mf = 0; mf < 4; mf++) {
      #pragma unroll
      for (int nf = 0; nf < 6; nf++) {
        #pragma unroll
        for (int r = 0; r < 4; r++) {
          int m = mf * 16 + hi * 4 + r;
          int col = wn + nf * 16 + lr;
          float z = acc[mf][nf][r] + b1[col];
          z = 0.5f * z * (1.f + erff(z * 0.70710678118654752f));
          int ch = col >> 3, e = col & 7;
          int chs = (ch & ~7) | ((ch & 7) ^ (m & 7));
          Htile[m * 768 + chs * 8 + e] = __float2bfloat16(z);
        }
      }
    }
  }
  __syncthreads();

  // ---- phase 2: out = h @ W2^T + b2 + x2; waves 2(M)x4(N), tile 32x48 ----
  {
    const int wm = (wave >> 2) * 32;
    const int wn = (wave & 3) * 48;
    f32x4 acc[2][3];
    #pragma unroll
    for (int i = 0; i < 2; i++)
      #pragma unroll
      for (int j = 0; j < 3; j++) acc[i][j] = (f32x4){0.f, 0.f, 0.f, 0.f};

    #pragma unroll
    for (int kk = 0; kk < 24; kk++) {      // K=768, 32/step
      short8 hf[2], wf[3];
      #pragma unroll
      for (int mf = 0; mf < 2; mf++) {
        int r = wm + mf * 16 + lr;
        int ch = kk * 4 + hi;
        int chs = (ch & ~7) | ((ch & 7) ^ (r & 7));
        hf[mf] = *(const short8*)&Htile[r * 768 + chs * 8];
      }
      #pragma unroll
      for (int nf = 0; nf < 3; nf++) {
        int n = wn + nf * 16 + lr;
        wf[nf] = *(const short8*)(W2 + (size_t)n * 768 + kk * 32 + hi * 8);
      }
      #pragma unroll
      for (int mf = 0; mf < 2; mf++)
        #pragma unroll
        for (int nf = 0; nf < 3; nf++)
          acc[mf][nf] = __builtin_amdgcn_mfma_f32_16x16x32_bf16(
              hf[mf], wf[nf], acc[mf][nf], 0, 0, 0);
    }

    #pragma unroll
    for (int mf = 0; mf < 2; mf++) {
      #pragma unroll
      for (int nf = 0; nf < 3; nf++) {
        #pragma unroll
        for (int r = 0; r < 4; r++) {
          int m = tok0 + wm + mf * 16 + hi * 4 + r;
          int n = wn + nf * 16 + lr;
          out[(size_t)m * 192 + n] = x2[(size_t)m * 192 + n] + acc[mf][nf][r] + b2[n];
        }
      }
    }
  }
}

// ---------------------------------------------------------------------------
// MFMA windowed attention: one wave per (window, head). Padded 49->64.
// ---------------------------------------------------------------------------
__global__ __launch_bounds__(64)
void attn_kernel(const __hip_bfloat16* __restrict__ qkv,
                 const __hip_bfloat16* __restrict__ smtab, // [64][6][64][64]
                 __hip_bfloat16* __restrict__ o)           // [MTOT][192]
{
  __shared__ char lds[12288] __attribute__((aligned(16)));  // P:0..8191 | vT:8192..12287
  const int b_   = blockIdx.x;
  const int head = blockIdx.y;
  const int l = threadIdx.x, c = l & 15, h = l >> 4;
  const size_t base = (size_t)b_ * 49 * 576;
  const int headoff = head * 32;

  // ---- stage V^T into LDS (keys >= 49 zeroed), swizzle byte^=((d&7)<<4) ----
  #pragma unroll
  for (int it = 0; it < 4; it++) {
    int u = l + it * 64;
    int row = u >> 2, c8 = u & 3;          // row = key 0..63, c8 = d-chunk
    short8 vv;
    if (row < 49) {
      vv = *(const short8*)(qkv + base + (size_t)row * 576 + 384 + headoff + c8 * 8);
    } else {
      #pragma unroll
      for (int e = 0; e < 8; e++) vv[e] = 0;
    }
    #pragma unroll
    for (int e = 0; e < 8; e++) {
      int d = c8 * 8 + e;
      *(short*)(lds + 8192 + ((d * 128 + row * 2) ^ ((d & 7) << 4))) = vv[e];
    }
  }

  // ---- Q,K fragments direct from global ----
  short8 aq[4], bk[4];
  #pragma unroll
  for (int t = 0; t < 4; t++) {
    int rowc = c + 16 * t; if (rowc > 48) rowc = 48;   // clamp padded rows
    const __hip_bfloat16* rp = qkv + base + (size_t)rowc * 576 + headoff + h * 8;
    aq[t] = *(const short8*)rp;          // Q
    bk[t] = *(const short8*)(rp + 192);  // K
  }

  // ---- S = Q*K^T : 16 MFMA ----
  f32x4 sacc[4][4];
  #pragma unroll
  for (int mi = 0; mi < 4; mi++)
    #pragma unroll
    for (int ni = 0; ni < 4; ni++)
      sacc[mi][ni] = (f32x4){0.f, 0.f, 0.f, 0.f};
  #pragma unroll
  for (int mi = 0; mi < 4; mi++)
    #pragma unroll
    for (int ni = 0; ni < 4; ni++)
      sacc[mi][ni] = __builtin_amdgcn_mfma_f32_16x16x32_bf16(
          aq[mi], bk[ni], sacc[mi][ni], 0, 0, 0);

  // ---- bias table + row softmax + P -> LDS ----
  const unsigned short* tb =
      (const unsigned short*)smtab + (((size_t)(b_ & 63) * 6 + head) << 12);
  float inv[4][4];
  #pragma unroll
  for (int mi = 0; mi < 4; mi++) {
    #pragma unroll
    for (int r = 0; r < 4; r++) {
      const int row = mi * 16 + h * 4 + r;   // query row (C-layout)
      float s[4];
      #pragma unroll
      for (int ni = 0; ni < 4; ni++)
        s[ni] = fmaf(sacc[mi][ni][r], SCALEQ, b2f(tb[row * 64 + ni * 16 + c]));
      float vmax = fmaxf(fmaxf(s[0], s[1]), fmaxf(s[2], s[3]));
      #pragma unroll
      for (int off = 1; off < 16; off <<= 1)
        vmax = fmaxf(vmax, __shfl_xor(vmax, off));
      float p[4], vsum = 0.f;
      #pragma unroll
      for (int ni = 0; ni < 4; ni++) { p[ni] = __expf(s[ni] - vmax); vsum += p[ni]; }
      #pragma unroll
      for (int off = 1; off < 16; off <<= 1)
        vsum += __shfl_xor(vsum, off);
      inv[mi][r] = 1.f / vsum;
      #pragma unroll
      for (int ni = 0; ni < 4; ni++) {
        int col = ni * 16 + c;
        *(__hip_bfloat16*)(lds + ((row * 128 + col * 2) ^ ((row & 7) << 4))) =
            __float2bfloat16(p[ni]);
      }
    }
  }
  __syncthreads();

  // ---- O = P*V ----
  f32x4 oacc[4][2];
  #pragma unroll
  for (int mt = 0; mt < 4; mt++)
    #pragma unroll
    for (int nt = 0; nt < 2; nt++)
      oacc[mt][nt] = (f32x4){0.f, 0.f, 0.f, 0.f};
  #pragma unroll
  for (int ks = 0; ks < 2; ks++) {
    short8 vb[2];
    #pragma unroll
    for (int nt = 0; nt < 2; nt++) {
      int d = c + 16 * nt;
      vb[nt] = *(const short8*)(lds + 8192 +
                ((d * 128 + h * 16 + ks * 64) ^ ((d & 7) << 4)));
    }
    #pragma unroll
    for (int mt = 0; mt < 4; mt++) {
      int qr = c + 16 * mt;
      short8 pa = *(const short8*)(lds +
                   ((qr * 128 + h * 16 + ks * 64) ^ ((qr & 7) << 4)));
      #pragma unroll
      for (int nt = 0; nt < 2; nt++)
        oacc[mt][nt] = __builtin_amdgcn_mfma_f32_16x16x32_bf16(
            pa, vb[nt], oacc[mt][nt], 0, 0, 0);
    }
  }

  // ---- store (q < 49 only), normalize by 1/rowsum ----
  #pragma unroll
  for (int mt = 0; mt < 4; mt++) {
    #pragma unroll
    for (int r = 0; r < 4; r++) {
      int q = mt * 16 + h * 4 + r;
      if (q < 49) {
        __hip_bfloat16* orow = o + ((size_t)b_ * 49 + q) * 192 + headoff;
        #pragma unroll
        for (int nt = 0; nt < 2; nt++)
          orow[nt * 16 + c] = __float2bfloat16(oacc[mt][nt][r] * inv[mt][r]);
      }
    }
  }
}

// ---------------------------------------------------------------------------
extern "C" void kernel_launch(void* const* d_in, const int* in_sizes, int n_in,
                              void* d_out, int out_size, void* d_ws, size_t ws_size,
                              hipStream_t stream)
{
  const float* x      = (const float*)d_in[0];
  const float* mask   = (const float*)d_in[1];
  const float* n1g    = (const float*)d_in[2];
  const float* n1b    = (const float*)d_in[3];
  const float* qkv_w  = (const float*)d_in[4];
  const float* qkv_b  = (const float*)d_in[5];
  const float* proj_w = (const float*)d_in[6];
  const float* proj_b = (const float*)d_in[7];
  const float* rpb    = (const float*)d_in[8];
  const float* n2g    = (const float*)d_in[9];
  const float* n2b    = (const float*)d_in[10];
  const float* fc1_w  = (const float*)d_in[11];
  const float* fc1_b  = (const float*)d_in[12];
  const float* fc2_w  = (const float*)d_in[13];
  const float* fc2_b  = (const float*)d_in[14];
  float* out = (float*)d_out;

  // Workspace layout (~188 MiB; x2 residual lives in d_out):
  const size_t offA = 0;
  const size_t offB = offA + (size_t)100352 * 768 * 2;
  const size_t offW = offB + (size_t)100352 * 192 * 2;
  const size_t offT = offW + (size_t)442368 * 2;
  const size_t needed = offT + (size_t)384 * 4096 * 2;
  if (ws_size < needed) return;  // avoid OOB writes if workspace is too small

  char* ws = (char*)d_ws;
  __hip_bfloat16* bufA = (__hip_bfloat16*)(ws + offA);
  __hip_bfloat16* bufB = (__hip_bfloat16*)(ws + offB);
  float*          x2   = out;   // residual stored in d_out, finalized in-place
  __hip_bfloat16* wq   = (__hip_bfloat16*)(ws + offW);
  __hip_bfloat16* wp   = wq + 576 * 192;
  __hip_bfloat16* w1   = wp + 192 * 192;
  __hip_bfloat16* w2   = w1 + 768 * 192;
  __hip_bfloat16* tab  = (__hip_bfloat16*)(ws + offT);

  // 1. weights -> bf16
  cvt4_kernel<<<1728, 256, 0, stream>>>(qkv_w, 576 * 192, proj_w, 192 * 192,
                                        fc1_w, 768 * 192, fc2_w, 192 * 768, wq);
  // 1b. softmax bias table
  smtab_kernel<<<384, 256, 0, stream>>>(mask, rpb, tab);
  // 2. LN1 + shift + window partition -> bf16 [MTOT][192]
  ln_kernel<true><<<MTOT / 4, 256, 0, stream>>>(x, n1g, n1b, bufB);
  // 3. qkv GEMM -> bf16 [MTOT][576]
  gemm_kernel<0, 192><<<dim3(576 / 64, MTOT / 128), 256, 0, stream>>>(
      bufB, wq, qkv_b, 576, bufA, nullptr);
  // 4. windowed attention (MFMA) -> bf16 [MTOT][192]
  attn_kernel<<<dim3(2048, 6), 64, 0, stream>>>(bufA, tab, bufB);
  // 5. proj GEMM + window-reverse + unshift + residual -> fp32 x2 (in d_out)
  gemm_kernel<2, 192><<<dim3(192 / 64, MTOT / 128), 256, 0, stream>>>(
      bufB, wp, proj_b, 192, x2, x);
  // 6. LN2 -> bf16
  ln_kernel<false><<<MTOT / 4, 256, 0, stream>>>(x2, n2g, n2b, bufB);
  // 7+8. fused MLP: out = GELU(ln2@W1^T+b1)@W2^T+b2 + x2  (in-place on d_out)
  mlp_kernel<<<MTOT / 64, 512, 0, stream>>>(bufB, w1, fc1_b, w2, fc2_b, x2, out);
}

// Round 14
// 456.331 us; speedup vs baseline: 1.0069x; 1.0069x over previous
//
#include <hip/hip_runtime.h>
#include <hip/hip_bf16.h>
#include <math.h>

// Problem constants
#define MTOT   100352        // B*H*W tokens = 2048 windows * 49
#define CC     192
#define SCALEQ 0.17677669529663687f   // 32^-0.5

typedef __attribute__((ext_vector_type(8))) short short8;
typedef __attribute__((ext_vector_type(4))) float f32x4;

__device__ __forceinline__ float b2f(unsigned short u) {
  return __uint_as_float(((unsigned int)u) << 16);
}

__device__ __forceinline__ void async_copy16(const void* g, void* l) {
  __builtin_amdgcn_global_load_lds(
      (const __attribute__((address_space(1))) unsigned int*)g,
      (__attribute__((address_space(3))) unsigned int*)l,
      16, 0, 0);
}

// ---------------------------------------------------------------------------
// Weight fp32 -> bf16 conversion (4 weight matrices concatenated into dst)
// ---------------------------------------------------------------------------
__global__ void cvt4_kernel(const float* __restrict__ s0, int n0,
                            const float* __restrict__ s1, int n1,
                            const float* __restrict__ s2, int n2,
                            const float* __restrict__ s3, int n3,
                            __hip_bfloat16* __restrict__ dst)
{
  int total = n0 + n1 + n2 + n3;
  for (int i = blockIdx.x * blockDim.x + threadIdx.x; i < total;
       i += gridDim.x * blockDim.x) {
    int j = i; const float* s;
    if (j < n0) s = s0;
    else { j -= n0; if (j < n1) s = s1;
      else { j -= n1; if (j < n2) s = s2; else { j -= n2; s = s3; } } }
    dst[i] = __float2bfloat16(s[j]);
  }
}

// ---------------------------------------------------------------------------
// Softmax-bias table: tab[wm][head][q64][k64] = rpb(q,k,head) + mask[wm][q][k]
// ---------------------------------------------------------------------------
__global__ __launch_bounds__(256)
void smtab_kernel(const float* __restrict__ mask, const float* __restrict__ rpb,
                  __hip_bfloat16* __restrict__ tab)
{
  const int wh = blockIdx.x;          // 0..383 = wm*6 + head
  const int wm = wh / 6, head = wh - wm * 6;
  for (int u = threadIdx.x; u < 4096; u += 256) {
    int q = u >> 6, k = u & 63;
    float v = -1e30f;
    if (q < 49 && k < 49) {
      int r1 = q / 7, s1 = q - r1 * 7, r2 = k / 7, s2 = k - r2 * 7;
      v = rpb[((r1 - r2 + 6) * 13 + (s1 - s2 + 6)) * 6 + head]
        + mask[wm * 2401 + q * 49 + k];
    }
    tab[(size_t)wh * 4096 + u] = __float2bfloat16(v);
  }
}

// ---------------------------------------------------------------------------
// LayerNorm (one wave per token). REMAP=true: fused roll(-3,-3)+window
// partition for LN1 (output in window-token order). REMAP=false: LN2.
// ---------------------------------------------------------------------------
template<bool REMAP>
__global__ __launch_bounds__(256)
void ln_kernel(const float* __restrict__ xin, const float* __restrict__ gam,
               const float* __restrict__ bet, __hip_bfloat16* __restrict__ out)
{
  const int wave = threadIdx.x >> 6, lane = threadIdx.x & 63;
  const int m = blockIdx.x * 4 + wave;
  size_t srow;
  if (REMAP) {
    int b_ = m / 49, n = m - b_ * 49;
    int b = b_ >> 6, widx = b_ & 63;
    int wh = widx >> 3, ww = widx & 7;
    int r = n / 7, s = n - r * 7;
    int h = wh * 7 + r, w = ww * 7 + s;
    int sh = h + 3; if (sh >= 56) sh -= 56;
    int sw = w + 3; if (sw >= 56) sw -= 56;
    srow = (size_t)b * 3136 + sh * 56 + sw;
  } else {
    srow = m;
  }
  const float* row = xin + srow * 192;
  float v0 = row[lane], v1 = row[lane + 64], v2 = row[lane + 128];
  float sum = v0 + v1 + v2;
  float sq  = v0 * v0 + v1 * v1 + v2 * v2;
  #pragma unroll
  for (int o = 1; o < 64; o <<= 1) {
    sum += __shfl_xor(sum, o);
    sq  += __shfl_xor(sq, o);
  }
  float mu = sum * (1.f / 192.f);
  float rs = rsqrtf(sq * (1.f / 192.f) - mu * mu + 1e-5f);
  __hip_bfloat16* orow = out + (size_t)m * 192;
  orow[lane]       = __float2bfloat16((v0 - mu) * rs * gam[lane]       + bet[lane]);
  orow[lane + 64]  = __float2bfloat16((v1 - mu) * rs * gam[lane + 64]  + bet[lane + 64]);
  orow[lane + 128] = __float2bfloat16((v2 - mu) * rs * gam[lane + 128] + bet[lane + 128]);
}

// ---------------------------------------------------------------------------
// bf16 MFMA GEMM (dbuf, swizzled, hoisted) — used for qkv (EPI 0) and
// proj (EPI 2). BM=128, BN=64, BK=64, 4 waves, acc[4][2].
// ---------------------------------------------------------------------------
template<int EPI, int K>
__global__ __launch_bounds__(256)
void gemm_kernel(const __hip_bfloat16* __restrict__ A,
                 const __hip_bfloat16* __restrict__ Wt,
                 const float* __restrict__ bias,
                 int Ntot,
                 void* __restrict__ outp,
                 const float* __restrict__ res)
{
  __shared__ __hip_bfloat16 smem[2][12288] __attribute__((aligned(16)));
  const int tid  = threadIdx.x;
  const int wave = tid >> 6;
  const int bn   = blockIdx.x * 64;
  const int bm   = blockIdx.y * 128;

  const int lr = tid & 15;
  const int hi = (tid >> 4) & 3;
  const int wm = (wave >> 1) * 64;
  const int wn = (wave & 1) * 32;

  const __hip_bfloat16* aptr[4];
  const __hip_bfloat16* bptr[2];
  int adst[4], bdst[2];
  #pragma unroll
  for (int p = 0; p < 4; p++) {
    int u = p * 256 + tid;
    int row = u >> 3;
    int c8 = (u & 7) ^ (row & 7);              // inverse swizzle on source
    aptr[p] = A + (size_t)(bm + row) * K + c8 * 8;
    adst[p] = (p * 256 + (wave << 6)) * 8;
  }
  #pragma unroll
  for (int p = 0; p < 2; p++) {
    int u = p * 256 + tid;
    int row = u >> 3;
    int c8 = (u & 7) ^ (row & 7);
    bptr[p] = Wt + (size_t)(bn + row) * K + c8 * 8;
    bdst[p] = 8192 + (p * 256 + (wave << 6)) * 8;
  }

  f32x4 acc[4][2];
  #pragma unroll
  for (int i = 0; i < 4; i++)
    #pragma unroll
    for (int j = 0; j < 2; j++) acc[i][j] = (f32x4){0.f, 0.f, 0.f, 0.f};

  const int KT = K / 64;

  #define STAGE(buf, k0)                                                      \
    do {                                                                      \
      _Pragma("unroll")                                                       \
      for (int p = 0; p < 4; p++)                                             \
        async_copy16(aptr[p] + (k0), &smem[buf][adst[p]]);                    \
      _Pragma("unroll")                                                       \
      for (int p = 0; p < 2; p++)                                             \
        async_copy16(bptr[p] + (k0), &smem[buf][bdst[p]]);                    \
    } while (0)

  STAGE(0, 0);
  __syncthreads();

  #pragma unroll
  for (int kt = 0; kt < KT; kt++) {
    const int cur = kt & 1;
    if (kt + 1 < KT) STAGE(cur ^ 1, (kt + 1) * 64);
    const __hip_bfloat16* sb = smem[cur];
    #pragma unroll
    for (int kk = 0; kk < 2; kk++) {
      short8 af[4], bfr[2];
      #pragma unroll
      for (int mf = 0; mf < 4; mf++) {
        int r = wm + mf * 16 + lr;
        af[mf] = *(const short8*)&sb[r * 64 + ((kk * 32 + hi * 8) ^ ((r & 7) * 8))];
      }
      #pragma unroll
      for (int nf = 0; nf < 2; nf++) {
        int r = wn + nf * 16 + lr;
        bfr[nf] = *(const short8*)&sb[8192 + r * 64 + ((kk * 32 + hi * 8) ^ ((r & 7) * 8))];
      }
      #pragma unroll
      for (int mf = 0; mf < 4; mf++)
        #pragma unroll
        for (int nf = 0; nf < 2; nf++)
          acc[mf][nf] = __builtin_amdgcn_mfma_f32_16x16x32_bf16(
              af[mf], bfr[nf], acc[mf][nf], 0, 0, 0);
    }
    __syncthreads();
  }
  #undef STAGE

  // Epilogue. C/D layout: col = lane&15, row = (lane>>4)*4 + reg.
  #pragma unroll
  for (int mf = 0; mf < 4; mf++) {
    #pragma unroll
    for (int nf = 0; nf < 2; nf++) {
      #pragma unroll
      for (int r = 0; r < 4; r++) {
        int m = bm + wm + mf * 16 + hi * 4 + r;
        int n = bn + wn + nf * 16 + lr;
        float z = acc[mf][nf][r] + bias[n];
        if (EPI == 0) {
          ((__hip_bfloat16*)outp)[(size_t)m * Ntot + n] = __float2bfloat16(z);
        } else {  // EPI == 2: proj + window-reverse + unshift + residual
          int b_ = m / 49, n49 = m - b_ * 49;
          int b = b_ >> 6, widx = b_ & 63;
          int wh = widx >> 3, ww = widx & 7;
          int rr = n49 / 7, ss = n49 - rr * 7;
          int h = wh * 7 + rr, w = ww * 7 + ss;
          int fh = h + 3; if (fh >= 56) fh -= 56;
          int fw = w + 3; if (fw >= 56) fw -= 56;
          size_t rowimg = (size_t)b * 3136 + fh * 56 + fw;
          ((float*)outp)[rowimg * 192 + n] = res[rowimg * 192 + n] + z;
        }
      }
    }
  }
}

// ---------------------------------------------------------------------------
// Fused MLP v2: out = GELU(ln2 @ W1^T + b1) @ W2^T + b2 + x2
// Block = 32 tokens, 256 thr (4 waves). h processed in 4 K-slices of 192,
// never materialized in HBM. Per round: ph1 computes h[:, slice] (wave w
// covers 48 cols, acc 2x3) -> GELU -> Htile (padded stride 200 elems to
// break bank-conflict pattern); ph2 accumulates out over that k-slice
// (persistent acc 2x3). LDS 25 KB -> 4+ blocks/CU (vs R13's 1). Weights
// L2-hot per-lane reads.
// ---------------------------------------------------------------------------
__global__ __launch_bounds__(256, 4)
void mlp_kernel(const __hip_bfloat16* __restrict__ ln2,   // [MTOT][192]
                const __hip_bfloat16* __restrict__ W1,    // [768][192]
                const float* __restrict__ b1,
                const __hip_bfloat16* __restrict__ W2,    // [192][768]
                const float* __restrict__ b2,
                const float* __restrict__ x2,             // [MTOT][192] fp32
                float* __restrict__ out)                  // [MTOT][192] fp32
{
  __shared__ __hip_bfloat16 Atile[6144] __attribute__((aligned(16)));  // 32x192
  __shared__ __hip_bfloat16 Htile[6400] __attribute__((aligned(16)));  // 32x200 (pad 8)
  const int tid  = threadIdx.x;
  const int wave = tid >> 6;           // 0..3
  const int lr   = tid & 15;
  const int hi   = (tid >> 4) & 3;
  const int tok0 = blockIdx.x * 32;
  const int wn   = wave * 48;          // wave's 48-col slice (of 192)

  // ---- stage A (32x192 bf16 = 12 KB): 3 passes x 256 thr x 16B ----
  // linear LDS dest; inverse-swizzled global source chunk (rule #21)
  #pragma unroll
  for (int p = 0; p < 3; p++) {
    int u = p * 256 + tid;               // chunk id 0..767
    int row = u / 24, c = u % 24;
    int csw = (c & ~7) | ((c & 7) ^ (row & 7));
    async_copy16(ln2 + (size_t)(tok0 + row) * 192 + csw * 8, &Atile[u * 8]);
  }

  f32x4 oacc[2][3];                    // persistent output accumulator
  #pragma unroll
  for (int i = 0; i < 2; i++)
    #pragma unroll
    for (int j = 0; j < 3; j++) oacc[i][j] = (f32x4){0.f, 0.f, 0.f, 0.f};

  __syncthreads();

  #pragma unroll
  for (int rd = 0; rd < 4; rd++) {     // h-slice [rd*192, rd*192+192)
    // ---- ph1: h slice cols wn..wn+47 (global rd*192+wn..) ----
    f32x4 hacc[2][3];
    #pragma unroll
    for (int i = 0; i < 2; i++)
      #pragma unroll
      for (int j = 0; j < 3; j++) hacc[i][j] = (f32x4){0.f, 0.f, 0.f, 0.f};

    #pragma unroll
    for (int kk = 0; kk < 6; kk++) {   // K=192
      short8 af[2], bfr[3];
      #pragma unroll
      for (int mf = 0; mf < 2; mf++) {
        int r = mf * 16 + lr;
        int ch = kk * 4 + hi;
        int chs = (ch & ~7) | ((ch & 7) ^ (r & 7));
        af[mf] = *(const short8*)&Atile[r * 192 + chs * 8];
      }
      #pragma unroll
      for (int nf = 0; nf < 3; nf++) {
        int n = rd * 192 + wn + nf * 16 + lr;
        bfr[nf] = *(const short8*)(W1 + (size_t)n * 192 + kk * 32 + hi * 8);
      }
      #pragma unroll
      for (int mf = 0; mf < 2; mf++)
        #pragma unroll
        for (int nf = 0; nf < 3; nf++)
          hacc[mf][nf] = __builtin_amdgcn_mfma_f32_16x16x32_bf16(
              af[mf], bfr[nf], hacc[mf][nf], 0, 0, 0);
    }
    // GELU -> Htile (swizzled chunks, padded stride 200)
    #pragma unroll
    for (int mf = 0; mf < 2; mf++) {
      #pragma unroll
      for (int nf = 0; nf < 3; nf++) {
        #pragma unroll
        for (int rr = 0; rr < 4; rr++) {
          int m  = mf * 16 + hi * 4 + rr;
          int cL = wn + nf * 16 + lr;            // local h col 0..191
          float z = hacc[mf][nf][rr] + b1[rd * 192 + cL];
          z = 0.5f * z * (1.f + erff(z * 0.70710678118654752f));
          int ch = cL >> 3, e = cL & 7;
          int chs = (ch & ~7) | ((ch & 7) ^ (m & 7));
          Htile[m * 200 + chs * 8 + e] = __float2bfloat16(z);
        }
      }
    }
    __syncthreads();

    // ---- ph2: out += h_slice @ W2_slice^T (wave cols wn..wn+47) ----
    #pragma unroll
    for (int kk = 0; kk < 6; kk++) {   // local k 0..191
      short8 hf[2], wf[3];
      #pragma unroll
      for (int mf = 0; mf < 2; mf++) {
        int r = mf * 16 + lr;
        int ch = kk * 4 + hi;
        int chs = (ch & ~7) | ((ch & 7) ^ (r & 7));
        hf[mf] = *(const short8*)&Htile[r * 200 + chs * 8];
      }
      #pragma unroll
      for (int nf = 0; nf < 3; nf++) {
        int n = wn + nf * 16 + lr;
        wf[nf] = *(const short8*)(W2 + (size_t)n * 768 + rd * 192 + kk * 32 + hi * 8);
      }
      #pragma unroll
      for (int mf = 0; mf < 2; mf++)
        #pragma unroll
        for (int nf = 0; nf < 3; nf++)
          oacc[mf][nf] = __builtin_amdgcn_mfma_f32_16x16x32_bf16(
              hf[mf], wf[nf], oacc[mf][nf], 0, 0, 0);
    }
    if (rd < 3) __syncthreads();       // guard Htile overwrite next round
  }

  // ---- epilogue: out = x2 + oacc + b2 ----
  #pragma unroll
  for (int mf = 0; mf < 2; mf++) {
    #pragma unroll
    for (int nf = 0; nf < 3; nf++) {
      #pragma unroll
      for (int rr = 0; rr < 4; rr++) {
        int m = tok0 + mf * 16 + hi * 4 + rr;
        int n = wn + nf * 16 + lr;
        out[(size_t)m * 192 + n] = x2[(size_t)m * 192 + n] + oacc[mf][nf][rr] + b2[n];
      }
    }
  }
}

// ---------------------------------------------------------------------------
// MFMA windowed attention: one wave per (window, head). Padded 49->64.
// ---------------------------------------------------------------------------
__global__ __launch_bounds__(64)
void attn_kernel(const __hip_bfloat16* __restrict__ qkv,
                 const __hip_bfloat16* __restrict__ smtab, // [64][6][64][64]
                 __hip_bfloat16* __restrict__ o)           // [MTOT][192]
{
  __shared__ char lds[12288] __attribute__((aligned(16)));  // P:0..8191 | vT:8192..12287
  const int b_   = blockIdx.x;
  const int head = blockIdx.y;
  const int l = threadIdx.x, c = l & 15, h = l >> 4;
  const size_t base = (size_t)b_ * 49 * 576;
  const int headoff = head * 32;

  // ---- stage V^T into LDS (keys >= 49 zeroed), swizzle byte^=((d&7)<<4) ----
  #pragma unroll
  for (int it = 0; it < 4; it++) {
    int u = l + it * 64;
    int row = u >> 2, c8 = u & 3;          // row = key 0..63, c8 = d-chunk
    short8 vv;
    if (row < 49) {
      vv = *(const short8*)(qkv + base + (size_t)row * 576 + 384 + headoff + c8 * 8);
    } else {
      #pragma unroll
      for (int e = 0; e < 8; e++) vv[e] = 0;
    }
    #pragma unroll
    for (int e = 0; e < 8; e++) {
      int d = c8 * 8 + e;
      *(short*)(lds + 8192 + ((d * 128 + row * 2) ^ ((d & 7) << 4))) = vv[e];
    }
  }

  // ---- Q,K fragments direct from global ----
  short8 aq[4], bk[4];
  #pragma unroll
  for (int t = 0; t < 4; t++) {
    int rowc = c + 16 * t; if (rowc > 48) rowc = 48;   // clamp padded rows
    const __hip_bfloat16* rp = qkv + base + (size_t)rowc * 576 + headoff + h * 8;
    aq[t] = *(const short8*)rp;          // Q
    bk[t] = *(const short8*)(rp + 192);  // K
  }

  // ---- S = Q*K^T : 16 MFMA ----
  f32x4 sacc[4][4];
  #pragma unroll
  for (int mi = 0; mi < 4; mi++)
    #pragma unroll
    for (int ni = 0; ni < 4; ni++)
      sacc[mi][ni] = (f32x4){0.f, 0.f, 0.f, 0.f};
  #pragma unroll
  for (int mi = 0; mi < 4; mi++)
    #pragma unroll
    for (int ni = 0; ni < 4; ni++)
      sacc[mi][ni] = __builtin_amdgcn_mfma_f32_16x16x32_bf16(
          aq[mi], bk[ni], sacc[mi][ni], 0, 0, 0);

  // ---- bias table + row softmax + P -> LDS ----
  const unsigned short* tb =
      (const unsigned short*)smtab + (((size_t)(b_ & 63) * 6 + head) << 12);
  float inv[4][4];
  #pragma unroll
  for (int mi = 0; mi < 4; mi++) {
    #pragma unroll
    for (int r = 0; r < 4; r++) {
      const int row = mi * 16 + h * 4 + r;   // query row (C-layout)
      float s[4];
      #pragma unroll
      for (int ni = 0; ni < 4; ni++)
        s[ni] = fmaf(sacc[mi][ni][r], SCALEQ, b2f(tb[row * 64 + ni * 16 + c]));
      float vmax = fmaxf(fmaxf(s[0], s[1]), fmaxf(s[2], s[3]));
      #pragma unroll
      for (int off = 1; off < 16; off <<= 1)
        vmax = fmaxf(vmax, __shfl_xor(vmax, off));
      float p[4], vsum = 0.f;
      #pragma unroll
      for (int ni = 0; ni < 4; ni++) { p[ni] = __expf(s[ni] - vmax); vsum += p[ni]; }
      #pragma unroll
      for (int off = 1; off < 16; off <<= 1)
        vsum += __shfl_xor(vsum, off);
      inv[mi][r] = 1.f / vsum;
      #pragma unroll
      for (int ni = 0; ni < 4; ni++) {
        int col = ni * 16 + c;
        *(__hip_bfloat16*)(lds + ((row * 128 + col * 2) ^ ((row & 7) << 4))) =
            __float2bfloat16(p[ni]);
      }
    }
  }
  __syncthreads();

  // ---- O = P*V ----
  f32x4 oacc[4][2];
  #pragma unroll
  for (int mt = 0; mt < 4; mt++)
    #pragma unroll
    for (int nt = 0; nt < 2; nt++)
      oacc[mt][nt] = (f32x4){0.f, 0.f, 0.f, 0.f};
  #pragma unroll
  for (int ks = 0; ks < 2; ks++) {
    short8 vb[2];
    #pragma unroll
    for (int nt = 0; nt < 2; nt++) {
      int d = c + 16 * nt;
      vb[nt] = *(const short8*)(lds + 8192 +
                ((d * 128 + h * 16 + ks * 64) ^ ((d & 7) << 4)));
    }
    #pragma unroll
    for (int mt = 0; mt < 4; mt++) {
      int qr = c + 16 * mt;
      short8 pa = *(const short8*)(lds +
                   ((qr * 128 + h * 16 + ks * 64) ^ ((qr & 7) << 4)));
      #pragma unroll
      for (int nt = 0; nt < 2; nt++)
        oacc[mt][nt] = __builtin_amdgcn_mfma_f32_16x16x32_bf16(
            pa, vb[nt], oacc[mt][nt], 0, 0, 0);
    }
  }

  // ---- store (q < 49 only), normalize by 1/rowsum ----
  #pragma unroll
  for (int mt = 0; mt < 4; mt++) {
    #pragma unroll
    for (int r = 0; r < 4; r++) {
      int q = mt * 16 + h * 4 + r;
      if (q < 49) {
        __hip_bfloat16* orow = o + ((size_t)b_ * 49 + q) * 192 + headoff;
        #pragma unroll
        for (int nt = 0; nt < 2; nt++)
          orow[nt * 16 + c] = __float2bfloat16(oacc[mt][nt][r] * inv[mt][r]);
      }
    }
  }
}

// ---------------------------------------------------------------------------
extern "C" void kernel_launch(void* const* d_in, const int* in_sizes, int n_in,
                              void* d_out, int out_size, void* d_ws, size_t ws_size,
                              hipStream_t stream)
{
  const float* x      = (const float*)d_in[0];
  const float* mask   = (const float*)d_in[1];
  const float* n1g    = (const float*)d_in[2];
  const float* n1b    = (const float*)d_in[3];
  const float* qkv_w  = (const float*)d_in[4];
  const float* qkv_b  = (const float*)d_in[5];
  const float* proj_w = (const float*)d_in[6];
  const float* proj_b = (const float*)d_in[7];
  const float* rpb    = (const float*)d_in[8];
  const float* n2g    = (const float*)d_in[9];
  const float* n2b    = (const float*)d_in[10];
  const float* fc1_w  = (const float*)d_in[11];
  const float* fc1_b  = (const float*)d_in[12];
  const float* fc2_w  = (const float*)d_in[13];
  const float* fc2_b  = (const float*)d_in[14];
  float* out = (float*)d_out;

  // Workspace layout (~188 MiB; x2 residual lives in d_out):
  const size_t offA = 0;
  const size_t offB = offA + (size_t)100352 * 768 * 2;
  const size_t offW = offB + (size_t)100352 * 192 * 2;
  const size_t offT = offW + (size_t)442368 * 2;
  const size_t needed = offT + (size_t)384 * 4096 * 2;
  if (ws_size < needed) return;  // avoid OOB writes if workspace is too small

  char* ws = (char*)d_ws;
  __hip_bfloat16* bufA = (__hip_bfloat16*)(ws + offA);
  __hip_bfloat16* bufB = (__hip_bfloat16*)(ws + offB);
  float*          x2   = out;   // residual stored in d_out, finalized in-place
  __hip_bfloat16* wq   = (__hip_bfloat16*)(ws + offW);
  __hip_bfloat16* wp   = wq + 576 * 192;
  __hip_bfloat16* w1   = wp + 192 * 192;
  __hip_bfloat16* w2   = w1 + 768 * 192;
  __hip_bfloat16* tab  = (__hip_bfloat16*)(ws + offT);

  // 1. weights -> bf16
  cvt4_kernel<<<1728, 256, 0, stream>>>(qkv_w, 576 * 192, proj_w, 192 * 192,
                                        fc1_w, 768 * 192, fc2_w, 192 * 768, wq);
  // 1b. softmax bias table
  smtab_kernel<<<384, 256, 0, stream>>>(mask, rpb, tab);
  // 2. LN1 + shift + window partition -> bf16 [MTOT][192]
  ln_kernel<true><<<MTOT / 4, 256, 0, stream>>>(x, n1g, n1b, bufB);
  // 3. qkv GEMM -> bf16 [MTOT][576]
  gemm_kernel<0, 192><<<dim3(576 / 64, MTOT / 128), 256, 0, stream>>>(
      bufB, wq, qkv_b, 576, bufA, nullptr);
  // 4. windowed attention (MFMA) -> bf16 [MTOT][192]
  attn_kernel<<<dim3(2048, 6), 64, 0, stream>>>(bufA, tab, bufB);
  // 5. proj GEMM + window-reverse + unshift + residual -> fp32 x2 (in d_out)
  gemm_kernel<2, 192><<<dim3(192 / 64, MTOT / 128), 256, 0, stream>>>(
      bufB, wp, proj_b, 192, x2, x);
  // 6. LN2 -> bf16
  ln_kernel<false><<<MTOT / 4, 256, 0, stream>>>(x2, n2g, n2b, bufB);
  // 7+8. fused MLP v2: out = GELU(ln2@W1^T+b1)@W2^T+b2 + x2 (in-place on d_out)
  mlp_kernel<<<MTOT / 32, 256, 0, stream>>>(bufB, w1, fc1_b, w2, fc2_b, x2, out);
}

// Round 15
// 385.228 us; speedup vs baseline: 1.1928x; 1.1846x over previous
//
#include <hip/hip_runtime.h>
#include <hip/hip_bf16.h>
#include <math.h>

// Problem constants
#define MTOT   100352        // B*H*W tokens = 2048 windows * 49
#define CC     192
#define SCALEQ 0.17677669529663687f   // 32^-0.5

typedef __attribute__((ext_vector_type(8))) short short8;
typedef __attribute__((ext_vector_type(4))) float f32x4;

__device__ __forceinline__ float b2f(unsigned short u) {
  return __uint_as_float(((unsigned int)u) << 16);
}

__device__ __forceinline__ void async_copy16(const void* g, void* l) {
  __builtin_amdgcn_global_load_lds(
      (const __attribute__((address_space(1))) unsigned int*)g,
      (__attribute__((address_space(3))) unsigned int*)l,
      16, 0, 0);
}

// ---------------------------------------------------------------------------
// Weight fp32 -> bf16 conversion (4 weight matrices concatenated into dst)
// ---------------------------------------------------------------------------
__global__ void cvt4_kernel(const float* __restrict__ s0, int n0,
                            const float* __restrict__ s1, int n1,
                            const float* __restrict__ s2, int n2,
                            const float* __restrict__ s3, int n3,
                            __hip_bfloat16* __restrict__ dst)
{
  int total = n0 + n1 + n2 + n3;
  for (int i = blockIdx.x * blockDim.x + threadIdx.x; i < total;
       i += gridDim.x * blockDim.x) {
    int j = i; const float* s;
    if (j < n0) s = s0;
    else { j -= n0; if (j < n1) s = s1;
      else { j -= n1; if (j < n2) s = s2; else { j -= n2; s = s3; } } }
    dst[i] = __float2bfloat16(s[j]);
  }
}

// ---------------------------------------------------------------------------
// Softmax-bias table: tab[wm][head][q64][k64] = rpb(q,k,head) + mask[wm][q][k]
// ---------------------------------------------------------------------------
__global__ __launch_bounds__(256)
void smtab_kernel(const float* __restrict__ mask, const float* __restrict__ rpb,
                  __hip_bfloat16* __restrict__ tab)
{
  const int wh = blockIdx.x;          // 0..383 = wm*6 + head
  const int wm = wh / 6, head = wh - wm * 6;
  for (int u = threadIdx.x; u < 4096; u += 256) {
    int q = u >> 6, k = u & 63;
    float v = -1e30f;
    if (q < 49 && k < 49) {
      int r1 = q / 7, s1 = q - r1 * 7, r2 = k / 7, s2 = k - r2 * 7;
      v = rpb[((r1 - r2 + 6) * 13 + (s1 - s2 + 6)) * 6 + head]
        + mask[wm * 2401 + q * 49 + k];
    }
    tab[(size_t)wh * 4096 + u] = __float2bfloat16(v);
  }
}

// ---------------------------------------------------------------------------
// LayerNorm (one wave per token). REMAP: fused roll(-3,-3)+window partition
// (LN1, fp32 input). BF16IN: input rows are bf16 (LN2 on bf16 x2).
// ---------------------------------------------------------------------------
template<bool REMAP, bool BF16IN>
__global__ __launch_bounds__(256)
void ln_kernel(const void* __restrict__ xin, const float* __restrict__ gam,
               const float* __restrict__ bet, __hip_bfloat16* __restrict__ out)
{
  const int wave = threadIdx.x >> 6, lane = threadIdx.x & 63;
  const int m = blockIdx.x * 4 + wave;
  size_t srow;
  if (REMAP) {
    int b_ = m / 49, n = m - b_ * 49;
    int b = b_ >> 6, widx = b_ & 63;
    int wh = widx >> 3, ww = widx & 7;
    int r = n / 7, s = n - r * 7;
    int h = wh * 7 + r, w = ww * 7 + s;
    int sh = h + 3; if (sh >= 56) sh -= 56;
    int sw = w + 3; if (sw >= 56) sw -= 56;
    srow = (size_t)b * 3136 + sh * 56 + sw;
  } else {
    srow = m;
  }
  float v0, v1, v2;
  if (BF16IN) {
    const unsigned short* row = (const unsigned short*)xin + srow * 192;
    v0 = b2f(row[lane]); v1 = b2f(row[lane + 64]); v2 = b2f(row[lane + 128]);
  } else {
    const float* row = (const float*)xin + srow * 192;
    v0 = row[lane]; v1 = row[lane + 64]; v2 = row[lane + 128];
  }
  float sum = v0 + v1 + v2;
  float sq  = v0 * v0 + v1 * v1 + v2 * v2;
  #pragma unroll
  for (int o = 1; o < 64; o <<= 1) {
    sum += __shfl_xor(sum, o);
    sq  += __shfl_xor(sq, o);
  }
  float mu = sum * (1.f / 192.f);
  float rs = rsqrtf(sq * (1.f / 192.f) - mu * mu + 1e-5f);
  __hip_bfloat16* orow = out + (size_t)m * 192;
  orow[lane]       = __float2bfloat16((v0 - mu) * rs * gam[lane]       + bet[lane]);
  orow[lane + 64]  = __float2bfloat16((v1 - mu) * rs * gam[lane + 64]  + bet[lane + 64]);
  orow[lane + 128] = __float2bfloat16((v2 - mu) * rs * gam[lane + 128] + bet[lane + 128]);
}

// ---------------------------------------------------------------------------
// bf16 MFMA GEMM (dbuf, swizzled, hoisted). BM=128, BN=64, BK=64, 4 waves.
// EPI: 0 = store bf16 (qkv)
//      1 = exact GELU, store bf16 (fc1)
//      2 = proj: window-reverse + roll + residual(fp32 x) -> fp32 x2
//      3 = fc2: + residual fp32 x2 -> fp32 out (in-place res==out ok)
//      4 = proj: window-reverse + roll + residual(fp32 x) -> bf16 x2
//      5 = fc2: + residual bf16 x2 -> fp32 out
// ---------------------------------------------------------------------------
template<int EPI, int K>
__global__ __launch_bounds__(256)
void gemm_kernel(const __hip_bfloat16* __restrict__ A,
                 const __hip_bfloat16* __restrict__ Wt,
                 const float* __restrict__ bias,
                 int Ntot,
                 void* __restrict__ outp,
                 const void* __restrict__ res)
{
  __shared__ __hip_bfloat16 smem[2][12288] __attribute__((aligned(16)));
  const int tid  = threadIdx.x;
  const int wave = tid >> 6;
  const int bn   = blockIdx.x * 64;
  const int bm   = blockIdx.y * 128;

  const int lr = tid & 15;
  const int hi = (tid >> 4) & 3;
  const int wm = (wave >> 1) * 64;
  const int wn = (wave & 1) * 32;

  const __hip_bfloat16* aptr[4];
  const __hip_bfloat16* bptr[2];
  int adst[4], bdst[2];
  #pragma unroll
  for (int p = 0; p < 4; p++) {
    int u = p * 256 + tid;
    int row = u >> 3;
    int c8 = (u & 7) ^ (row & 7);              // inverse swizzle on source
    aptr[p] = A + (size_t)(bm + row) * K + c8 * 8;
    adst[p] = (p * 256 + (wave << 6)) * 8;
  }
  #pragma unroll
  for (int p = 0; p < 2; p++) {
    int u = p * 256 + tid;
    int row = u >> 3;
    int c8 = (u & 7) ^ (row & 7);
    bptr[p] = Wt + (size_t)(bn + row) * K + c8 * 8;
    bdst[p] = 8192 + (p * 256 + (wave << 6)) * 8;
  }

  f32x4 acc[4][2];
  #pragma unroll
  for (int i = 0; i < 4; i++)
    #pragma unroll
    for (int j = 0; j < 2; j++) acc[i][j] = (f32x4){0.f, 0.f, 0.f, 0.f};

  const int KT = K / 64;

  #define STAGE(buf, k0)                                                      \
    do {                                                                      \
      _Pragma("unroll")                                                       \
      for (int p = 0; p < 4; p++)                                             \
        async_copy16(aptr[p] + (k0), &smem[buf][adst[p]]);                    \
      _Pragma("unroll")                                                       \
      for (int p = 0; p < 2; p++)                                             \
        async_copy16(bptr[p] + (k0), &smem[buf][bdst[p]]);                    \
    } while (0)

  STAGE(0, 0);
  __syncthreads();

  #pragma unroll
  for (int kt = 0; kt < KT; kt++) {
    const int cur = kt & 1;
    if (kt + 1 < KT) STAGE(cur ^ 1, (kt + 1) * 64);
    const __hip_bfloat16* sb = smem[cur];
    #pragma unroll
    for (int kk = 0; kk < 2; kk++) {
      short8 af[4], bfr[2];
      #pragma unroll
      for (int mf = 0; mf < 4; mf++) {
        int r = wm + mf * 16 + lr;
        af[mf] = *(const short8*)&sb[r * 64 + ((kk * 32 + hi * 8) ^ ((r & 7) * 8))];
      }
      #pragma unroll
      for (int nf = 0; nf < 2; nf++) {
        int r = wn + nf * 16 + lr;
        bfr[nf] = *(const short8*)&sb[8192 + r * 64 + ((kk * 32 + hi * 8) ^ ((r & 7) * 8))];
      }
      #pragma unroll
      for (int mf = 0; mf < 4; mf++)
        #pragma unroll
        for (int nf = 0; nf < 2; nf++)
          acc[mf][nf] = __builtin_amdgcn_mfma_f32_16x16x32_bf16(
              af[mf], bfr[nf], acc[mf][nf], 0, 0, 0);
    }
    __syncthreads();
  }
  #undef STAGE

  // Epilogue. C/D layout: col = lane&15, row = (lane>>4)*4 + reg.
  #pragma unroll
  for (int mf = 0; mf < 4; mf++) {
    #pragma unroll
    for (int nf = 0; nf < 2; nf++) {
      #pragma unroll
      for (int r = 0; r < 4; r++) {
        int m = bm + wm + mf * 16 + hi * 4 + r;
        int n = bn + wn + nf * 16 + lr;
        float z = acc[mf][nf][r] + bias[n];
        if (EPI == 0) {
          ((__hip_bfloat16*)outp)[(size_t)m * Ntot + n] = __float2bfloat16(z);
        } else if (EPI == 1) {
          z = 0.5f * z * (1.f + erff(z * 0.70710678118654752f));
          ((__hip_bfloat16*)outp)[(size_t)m * Ntot + n] = __float2bfloat16(z);
        } else if (EPI == 2 || EPI == 4) {
          int b_ = m / 49, n49 = m - b_ * 49;
          int b = b_ >> 6, widx = b_ & 63;
          int wh = widx >> 3, ww = widx & 7;
          int rr = n49 / 7, ss = n49 - rr * 7;
          int h = wh * 7 + rr, w = ww * 7 + ss;
          int fh = h + 3; if (fh >= 56) fh -= 56;
          int fw = w + 3; if (fw >= 56) fw -= 56;
          size_t rowimg = (size_t)b * 3136 + fh * 56 + fw;
          float v = ((const float*)res)[rowimg * 192 + n] + z;
          if (EPI == 2) ((float*)outp)[rowimg * 192 + n] = v;
          else ((__hip_bfloat16*)outp)[rowimg * 192 + n] = __float2bfloat16(v);
        } else if (EPI == 3) {
          ((float*)outp)[(size_t)m * 192 + n] =
              ((const float*)res)[(size_t)m * 192 + n] + z;
        } else {  // EPI == 5
          ((float*)outp)[(size_t)m * 192 + n] =
              b2f(((const unsigned short*)res)[(size_t)m * 192 + n]) + z;
        }
      }
    }
  }
}

// ---------------------------------------------------------------------------
// MFMA windowed attention: one wave per (window, head). Padded 49->64.
// ---------------------------------------------------------------------------
__global__ __launch_bounds__(64)
void attn_kernel(const __hip_bfloat16* __restrict__ qkv,
                 const __hip_bfloat16* __restrict__ smtab, // [64][6][64][64]
                 __hip_bfloat16* __restrict__ o)           // [MTOT][192]
{
  __shared__ char lds[12288] __attribute__((aligned(16)));  // P:0..8191 | vT:8192..12287
  const int b_   = blockIdx.x;
  const int head = blockIdx.y;
  const int l = threadIdx.x, c = l & 15, h = l >> 4;
  const size_t base = (size_t)b_ * 49 * 576;
  const int headoff = head * 32;

  // ---- stage V^T into LDS (keys >= 49 zeroed), swizzle byte^=((d&7)<<4) ----
  #pragma unroll
  for (int it = 0; it < 4; it++) {
    int u = l + it * 64;
    int row = u >> 2, c8 = u & 3;          // row = key 0..63, c8 = d-chunk
    short8 vv;
    if (row < 49) {
      vv = *(const short8*)(qkv + base + (size_t)row * 576 + 384 + headoff + c8 * 8);
    } else {
      #pragma unroll
      for (int e = 0; e < 8; e++) vv[e] = 0;
    }
    #pragma unroll
    for (int e = 0; e < 8; e++) {
      int d = c8 * 8 + e;
      *(short*)(lds + 8192 + ((d * 128 + row * 2) ^ ((d & 7) << 4))) = vv[e];
    }
  }

  // ---- Q,K fragments direct from global ----
  short8 aq[4], bk[4];
  #pragma unroll
  for (int t = 0; t < 4; t++) {
    int rowc = c + 16 * t; if (rowc > 48) rowc = 48;   // clamp padded rows
    const __hip_bfloat16* rp = qkv + base + (size_t)rowc * 576 + headoff + h * 8;
    aq[t] = *(const short8*)rp;          // Q
    bk[t] = *(const short8*)(rp + 192);  // K
  }

  // ---- S = Q*K^T : 16 MFMA ----
  f32x4 sacc[4][4];
  #pragma unroll
  for (int mi = 0; mi < 4; mi++)
    #pragma unroll
    for (int ni = 0; ni < 4; ni++)
      sacc[mi][ni] = (f32x4){0.f, 0.f, 0.f, 0.f};
  #pragma unroll
  for (int mi = 0; mi < 4; mi++)
    #pragma unroll
    for (int ni = 0; ni < 4; ni++)
      sacc[mi][ni] = __builtin_amdgcn_mfma_f32_16x16x32_bf16(
          aq[mi], bk[ni], sacc[mi][ni], 0, 0, 0);

  // ---- bias table + row softmax + P -> LDS ----
  const unsigned short* tb =
      (const unsigned short*)smtab + (((size_t)(b_ & 63) * 6 + head) << 12);
  float inv[4][4];
  #pragma unroll
  for (int mi = 0; mi < 4; mi++) {
    #pragma unroll
    for (int r = 0; r < 4; r++) {
      const int row = mi * 16 + h * 4 + r;   // query row (C-layout)
      float s[4];
      #pragma unroll
      for (int ni = 0; ni < 4; ni++)
        s[ni] = fmaf(sacc[mi][ni][r], SCALEQ, b2f(tb[row * 64 + ni * 16 + c]));
      float vmax = fmaxf(fmaxf(s[0], s[1]), fmaxf(s[2], s[3]));
      #pragma unroll
      for (int off = 1; off < 16; off <<= 1)
        vmax = fmaxf(vmax, __shfl_xor(vmax, off));
      float p[4], vsum = 0.f;
      #pragma unroll
      for (int ni = 0; ni < 4; ni++) { p[ni] = __expf(s[ni] - vmax); vsum += p[ni]; }
      #pragma unroll
      for (int off = 1; off < 16; off <<= 1)
        vsum += __shfl_xor(vsum, off);
      inv[mi][r] = 1.f / vsum;
      #pragma unroll
      for (int ni = 0; ni < 4; ni++) {
        int col = ni * 16 + c;
        *(__hip_bfloat16*)(lds + ((row * 128 + col * 2) ^ ((row & 7) << 4))) =
            __float2bfloat16(p[ni]);
      }
    }
  }
  __syncthreads();

  // ---- O = P*V ----
  f32x4 oacc[4][2];
  #pragma unroll
  for (int mt = 0; mt < 4; mt++)
    #pragma unroll
    for (int nt = 0; nt < 2; nt++)
      oacc[mt][nt] = (f32x4){0.f, 0.f, 0.f, 0.f};
  #pragma unroll
  for (int ks = 0; ks < 2; ks++) {
    short8 vb[2];
    #pragma unroll
    for (int nt = 0; nt < 2; nt++) {
      int d = c + 16 * nt;
      vb[nt] = *(const short8*)(lds + 8192 +
                ((d * 128 + h * 16 + ks * 64) ^ ((d & 7) << 4)));
    }
    #pragma unroll
    for (int mt = 0; mt < 4; mt++) {
      int qr = c + 16 * mt;
      short8 pa = *(const short8*)(lds +
                   ((qr * 128 + h * 16 + ks * 64) ^ ((qr & 7) << 4)));
      #pragma unroll
      for (int nt = 0; nt < 2; nt++)
        oacc[mt][nt] = __builtin_amdgcn_mfma_f32_16x16x32_bf16(
            pa, vb[nt], oacc[mt][nt], 0, 0, 0);
    }
  }

  // ---- store (q < 49 only), normalize by 1/rowsum ----
  #pragma unroll
  for (int mt = 0; mt < 4; mt++) {
    #pragma unroll
    for (int r = 0; r < 4; r++) {
      int q = mt * 16 + h * 4 + r;
      if (q < 49) {
        __hip_bfloat16* orow = o + ((size_t)b_ * 49 + q) * 192 + headoff;
        #pragma unroll
        for (int nt = 0; nt < 2; nt++)
          orow[nt * 16 + c] = __float2bfloat16(oacc[mt][nt][r] * inv[mt][r]);
      }
    }
  }
}

// ---------------------------------------------------------------------------
extern "C" void kernel_launch(void* const* d_in, const int* in_sizes, int n_in,
                              void* d_out, int out_size, void* d_ws, size_t ws_size,
                              hipStream_t stream)
{
  const float* x      = (const float*)d_in[0];
  const float* mask   = (const float*)d_in[1];
  const float* n1g    = (const float*)d_in[2];
  const float* n1b    = (const float*)d_in[3];
  const float* qkv_w  = (const float*)d_in[4];
  const float* qkv_b  = (const float*)d_in[5];
  const float* proj_w = (const float*)d_in[6];
  const float* proj_b = (const float*)d_in[7];
  const float* rpb    = (const float*)d_in[8];
  const float* n2g    = (const float*)d_in[9];
  const float* n2b    = (const float*)d_in[10];
  const float* fc1_w  = (const float*)d_in[11];
  const float* fc1_b  = (const float*)d_in[12];
  const float* fc2_w  = (const float*)d_in[13];
  const float* fc2_b  = (const float*)d_in[14];
  float* out = (float*)d_out;

  // Workspace layout:
  //   A: 154.1 MB (qkv out, later fc1/GELU out)
  //   B:  38.5 MB (xw, attn-out, LN2 out)
  //   W:  0.9 MB  bf16 weights   T: 3.1 MB softmax table
  //   X:  38.5 MB bf16 x2 residual (optional — only if ws_size permits)
  const size_t offA = 0;
  const size_t offB = offA + (size_t)100352 * 768 * 2;
  const size_t offW = offB + (size_t)100352 * 192 * 2;
  const size_t offT = offW + (size_t)442368 * 2;
  const size_t needBase = offT + (size_t)384 * 4096 * 2;
  const size_t offX = needBase;
  const size_t needX = needBase + (size_t)100352 * 192 * 2;
  if (ws_size < needBase) return;  // avoid OOB writes
  const bool useX = (ws_size >= needX);

  char* ws = (char*)d_ws;
  __hip_bfloat16* bufA = (__hip_bfloat16*)(ws + offA);
  __hip_bfloat16* bufB = (__hip_bfloat16*)(ws + offB);
  __hip_bfloat16* wq   = (__hip_bfloat16*)(ws + offW);
  __hip_bfloat16* wp   = wq + 576 * 192;
  __hip_bfloat16* w1   = wp + 192 * 192;
  __hip_bfloat16* w2   = w1 + 768 * 192;
  __hip_bfloat16* tab  = (__hip_bfloat16*)(ws + offT);
  __hip_bfloat16* x2b  = (__hip_bfloat16*)(ws + offX);   // bf16 x2 (useX)
  float*          x2f  = out;                            // fp32 x2 (fallback)

  // 1. weights -> bf16
  cvt4_kernel<<<1728, 256, 0, stream>>>(qkv_w, 576 * 192, proj_w, 192 * 192,
                                        fc1_w, 768 * 192, fc2_w, 192 * 768, wq);
  // 1b. softmax bias table
  smtab_kernel<<<384, 256, 0, stream>>>(mask, rpb, tab);
  // 2. LN1 + shift + window partition -> bf16 [MTOT][192]
  ln_kernel<true, false><<<MTOT / 4, 256, 0, stream>>>(x, n1g, n1b, bufB);
  // 3. qkv GEMM -> bf16 [MTOT][576]
  gemm_kernel<0, 192><<<dim3(9, MTOT / 128), 256, 0, stream>>>(
      bufB, wq, qkv_b, 576, bufA, nullptr);
  // 4. windowed attention (MFMA) -> bf16 [MTOT][192]
  attn_kernel<<<dim3(2048, 6), 64, 0, stream>>>(bufA, tab, bufB);

  if (useX) {
    // 5. proj + window-reverse + unshift + residual -> bf16 x2
    gemm_kernel<4, 192><<<dim3(3, MTOT / 128), 256, 0, stream>>>(
        bufB, wp, proj_b, 192, x2b, x);
    // 6. LN2 (bf16 input) -> bf16
    ln_kernel<false, true><<<MTOT / 4, 256, 0, stream>>>(x2b, n2g, n2b, bufB);
    // 7. fc1 + GELU -> bf16 [MTOT][768]
    gemm_kernel<1, 192><<<dim3(12, MTOT / 128), 256, 0, stream>>>(
        bufB, w1, fc1_b, 768, bufA, nullptr);
    // 8. fc2 + residual(bf16 x2) -> fp32 out
    gemm_kernel<5, 768><<<dim3(3, MTOT / 128), 256, 0, stream>>>(
        bufA, w2, fc2_b, 192, out, x2b);
  } else {
    // 5. proj + window-reverse + unshift + residual -> fp32 x2 (in d_out)
    gemm_kernel<2, 192><<<dim3(3, MTOT / 128), 256, 0, stream>>>(
        bufB, wp, proj_b, 192, x2f, x);
    // 6. LN2 (fp32 input) -> bf16
    ln_kernel<false, false><<<MTOT / 4, 256, 0, stream>>>(x2f, n2g, n2b, bufB);
    // 7. fc1 + GELU -> bf16 [MTOT][768]
    gemm_kernel<1, 192><<<dim3(12, MTOT / 128), 256, 0, stream>>>(
        bufB, w1, fc1_b, 768, bufA, nullptr);
    // 8. fc2 + residual(fp32 x2, in-place on d_out) -> fp32 out
    gemm_kernel<3, 768><<<dim3(3, MTOT / 128), 256, 0, stream>>>(
        bufA, w2, fc2_b, 192, out, x2f);
  }
}